// Round 1
// 203.517 us; speedup vs baseline: 1.0219x; 1.0219x over previous
//
#include <hip/hip_runtime.h>
#include <hip/hip_bf16.h>

// DecoderCBatchNorm, round 10: barrier-free MLP + LDS weight table.
// - ALL LDS dependencies are wave-private (phase-1 rows 16wv..16wv+15 ==
//   floats [576wv,576wv+576) == wave wv's phase-2 cf/transpose region), so
//   the 17 block-wide __syncthreads (each a full vmcnt/lgkmcnt drain + 8-wave
//   lockstep) are replaced by per-wave "s_waitcnt lgkmcnt(0)" fences. One
//   real barrier remains, covering the cooperative weight staging.
// - W0/W1 pre-packed to bf16 MFMA B-fragments in LDS (20 KB) + biases
//   (2.5 KB) once per block: per-stage access is 4x ds_read_b128 + 4
//   broadcast ds_read_b32 instead of 32 scalar global loads + 16 pk2 per
//   wave per stage (all 4096 waves were re-reading the same 40 KB).
// - p/MAX_DIM stashed in the spare 4 floats of each 36-wide xb row during
//   phase 1 (0.55 folded into fc_p_W), removing 12 scalar p re-loads/lane.
// - Keeps round-9 XCD-aware batch swizzle + const-div strength reduction.
// B=16, T=4096, L=4, H=W=128, D=32. Output [B,T] f32.

#define LL 4
#define HH 128
#define WW 128
#define DD 32
#define NPT 65536

typedef __attribute__((ext_vector_type(8))) short bf16x8t;
typedef __attribute__((ext_vector_type(4))) float f32x4;

union ABfrag { bf16x8t v; unsigned u[4]; };

__device__ __forceinline__ unsigned pk2(float a, float b) {
    __hip_bfloat16 ha = __float2bfloat16(a);   // RNE
    __hip_bfloat16 hb = __float2bfloat16(b);
    unsigned short ua = *reinterpret_cast<unsigned short*>(&ha);
    unsigned short ub = *reinterpret_cast<unsigned short*>(&hb);
    return (unsigned)ua | ((unsigned)ub << 16);
}

// Intra-wave LDS RAW fence: lgkmcnt(0) guarantees this wave's ds_writes have
// committed before any ds_read issued after the fence (memory clobber stops
// the compiler from hoisting those reads). WAR hazards in this kernel are
// ordered by register consumption, so this is the only fence needed.
__device__ __forceinline__ void lds_fence() {
    asm volatile("s_waitcnt lgkmcnt(0)" ::: "memory");
}

__global__ __launch_bounds__(512, 2) void decoder_fused_mfma(
    const float* __restrict__ p,        // [B,T,3]
    const float* __restrict__ c,        // [B,L,H,W,D]
    const float* __restrict__ Cmat,     // [B,L,4,3]
    const float* __restrict__ fc_p_W,   // [3,32]
    const float* __restrict__ fc_p_b,   // [32]
    const float* __restrict__ W0,       // [5,32,32]
    const float* __restrict__ b0,       // [5,32]
    const float* __restrict__ W1,       // [5,32,32]
    const float* __restrict__ b1,       // [5,32]
    const float* __restrict__ fc_out_W, // [32]
    const float* __restrict__ fc_out_b, // [1]
    float* __restrict__ out)            // [B,T]
{
    // Phase 1: cf[pt][ch] at xb[pt*36 + ch], p/0.55 at xb[pt*36 + 32..34]
    // Phase 2: per-wave 16x36 A-transpose staging, ALIASED (wave wv at +wv*576)
    __shared__ __align__(16) float xb[4608];
    __shared__ uint4 wtab[1280];   // [s*4 + m*2 + tile][lane] bf16 B-fragments
    __shared__ float btab[640];    // b0 (5x32) then b1 (5x32)

    const int tid = threadIdx.x;

    // XCD-aware swizzle: i%8 ~ XCD. batch = (i&7) + 8*(i>>8) in {0..15};
    // block-within-batch = (i>>3)&31. All 32 blocks of a batch share an XCD.
    const int i    = blockIdx.x;                 // 0..511
    const int b_u  = (i & 7) + ((i >> 8) << 3);  // batch
    const int blk  = (i >> 3) & 31;              // block within batch
    const int tbase = b_u * 4096 + blk * 128;    // first point of this block

    const float inv_maxdim   = 1.0f / 0.55f;
    const float inv_interval = 1.0f / (float)(2.0 / 127.0);   // ~63.5

    // ====================================== phase 0: weight staging -> LDS ==
    // 1280 fragments: idx = s*4 + m*2 + tile (m: 0=W0, 1=W1), 64 lanes each.
    for (int f = tid; f < 1280; f += 512) {
        const int ln   = f & 63;
        const int idx  = f >> 6;        // 0..19
        const int tile = idx & 1;
        const int m    = (idx >> 1) & 1;
        const int s    = idx >> 2;      // 0..4
        const int cchf = ln & 15;
        const int qf   = ln >> 4;
        const float* base = (m ? W1 : W0) + s * DD * DD + tile * 16 + cchf;
        uint4 w;
        w.x = pk2(base[(8 * qf + 0) * DD], base[(8 * qf + 1) * DD]);
        w.y = pk2(base[(8 * qf + 2) * DD], base[(8 * qf + 3) * DD]);
        w.z = pk2(base[(8 * qf + 4) * DD], base[(8 * qf + 5) * DD]);
        w.w = pk2(base[(8 * qf + 6) * DD], base[(8 * qf + 7) * DD]);
        wtab[f] = w;
    }
    for (int f = tid; f < 640; f += 512)
        btab[f] = (f < 320) ? b0[f] : b1[f - 320];

    // ================================================== phase 1: gather ====
    {
        const int tl = tid >> 2;                    // local point 0..127
        const int dg = tid & 3;                     // channel octet 0..3
        const int t  = tbase + tl;

        const float* pp = p + (size_t)t * 3;
        const float pm0 = pp[0] * inv_maxdim;
        const float pm1 = pp[1] * inv_maxdim;
        const float pm2 = pp[2] * inv_maxdim;

        // stash scaled p for phase 2 (wave-private rows; spare cols 32..34)
        if (dg == 0) {
            xb[tl * 36 + 32] = pm0;
            xb[tl * 36 + 33] = pm1;
            xb[tl * 36 + 34] = pm2;
        }

        float acc[8];
        #pragma unroll
        for (int ii = 0; ii < 8; ++ii) acc[ii] = 0.0f;

        #pragma unroll
        for (int l = 0; l < LL; ++l) {
            const float* cm = Cmat + (size_t)(b_u * LL + l) * 12;
            const float c00 = cm[0], c01 = cm[1], c02 = cm[2];
            const float c10 = cm[3], c11 = cm[4], c12 = cm[5];
            const float c30 = cm[9];

            float pr0 = c00 * pm0 + c01 * pm1 + c02 * pm2;
            float pr1 = c10 * pm0 + c11 * pm1 + c12 * pm2;
            const float denom = c30 + 0.05f;
            pr0 = pr0 / denom;                       // exact (denom varies)
            pr1 = pr1 / denom;

            float xg = (pr0 + 1.0f) * inv_interval;
            float yg = (pr1 + 1.0f) * inv_interval;
            xg = (xg >= 127.0f) ? 126.9f : xg;
            xg = (xg < 0.0f)    ? 0.0f   : xg;
            yg = (yg >= 127.0f) ? 126.9f : yg;
            yg = (yg < 0.0f)    ? 0.0f   : yg;

            const float xl = rintf(xg - 0.5f);
            const float xr = rintf(xg + 0.5f);
            const float yl = rintf(yg - 0.5f);
            const float yh = rintf(yg + 0.5f);
            const int xil = (int)xl, xir = (int)xr, yil = (int)yl, yih = (int)yh;

            const float dx = xr - xg;
            const float dy = yh - yg;
            const float w11 = dx * dy;
            const float w12 = (1.0f - dx) * dy;
            const float w21 = dx * (1.0f - dy);
            const float w22 = (1.0f - dx) * (1.0f - dy);

            const float* plane = c + (size_t)(b_u * LL + l) * (HH * WW * DD);
            const int doff = dg * 8;
            const float* t11 = plane + ((size_t)xil * WW + yil) * DD + doff;
            const float* t12 = plane + ((size_t)xir * WW + yil) * DD + doff;
            const float* t21 = plane + ((size_t)xil * WW + yih) * DD + doff;
            const float* t22 = plane + ((size_t)xir * WW + yih) * DD + doff;

            #pragma unroll
            for (int hf = 0; hf < 2; ++hf) {
                const float4 a  = *(const float4*)(t11 + 4 * hf);
                const float4 e  = *(const float4*)(t12 + 4 * hf);
                const float4 g  = *(const float4*)(t21 + 4 * hf);
                const float4 d4 = *(const float4*)(t22 + 4 * hf);
                acc[4*hf + 0] += w11 * a.x + w12 * e.x + w21 * g.x + w22 * d4.x;
                acc[4*hf + 1] += w11 * a.y + w12 * e.y + w21 * g.y + w22 * d4.y;
                acc[4*hf + 2] += w11 * a.z + w12 * e.z + w21 * g.z + w22 * d4.z;
                acc[4*hf + 3] += w11 * a.w + w12 * e.w + w21 * g.w + w22 * d4.w;
            }
        }

        float* dst = xb + tl * 36 + dg * 8;
        *(float4*)(dst)     = make_float4(acc[0], acc[1], acc[2], acc[3]);
        *(float4*)(dst + 4) = make_float4(acc[4], acc[5], acc[6], acc[7]);
    }

    // ONLY barrier: makes the cross-wave weight/bias tables visible.
    // (xb producer == consumer wave, so it needs no barrier at all.)
    __syncthreads();

    // ================================================== phase 2: MFMA MLP ==
    const int lane = tid & 63;
    const int wv   = tid >> 6;              // wave 0..7
    const int cch  = lane & 15;             // channel-in-tile / C col / A row
    const int q    = lane >> 4;             // quad 0..3
    const int tl0  = wv * 16;               // first local point of this wave
    const int tpt  = tbase + tl0;

    // cf -> C-layout registers (row = 4q+r, col = cch / cch+16)
    f32x4 cf0, cf1;
    #pragma unroll
    for (int r = 0; r < 4; ++r) {
        const int ptl = tl0 + q * 4 + r;
        cf0[r] = xb[ptl * 36 + cch];
        cf1[r] = xb[ptl * 36 + 16 + cch];
    }

    // fc_p params; fold the /0.55 of the stashed p back into the weights
    const float fpb0 = fc_p_b[cch],                fpb1 = fc_p_b[16 + cch];
    const float fw00 = fc_p_W[cch] * 0.55f,        fw01 = fc_p_W[16 + cch] * 0.55f;
    const float fw10 = fc_p_W[DD + cch] * 0.55f,   fw11 = fc_p_W[DD + 16 + cch] * 0.55f;
    const float fw20 = fc_p_W[2*DD + cch] * 0.55f, fw21 = fc_p_W[2*DD + 16 + cch] * 0.55f;

    f32x4 net0, net1;
    #pragma unroll
    for (int r = 0; r < 4; ++r) {
        const int ptl = tl0 + q * 4 + r;
        const float px = xb[ptl * 36 + 32];   // p/0.55 (broadcast reads)
        const float py = xb[ptl * 36 + 33];
        const float pz = xb[ptl * 36 + 34];
        net0[r] = fpb0 + px * fw00 + py * fw10 + pz * fw20 + cf0[r];
        net1[r] = fpb1 + px * fw01 + py * fw11 + pz * fw21 + cf1[r];
    }

    // xb reuse as transpose staging is safe without a barrier: the cf/p reads
    // above are consumed into registers before any ds_write below is issued.
    float* myxb = xb + wv * 576;   // 16 rows x 36 (wave-private region)

    #pragma unroll
    for (int s = 0; s < 5; ++s) {
        const float bc00 = btab[s * DD + cch];
        const float bc01 = btab[s * DD + 16 + cch];
        const float bc10 = btab[320 + s * DD + cch];
        const float bc11 = btab[320 + s * DD + 16 + cch];

        if (s > 0) {
            #pragma unroll
            for (int r = 0; r < 4; ++r) { net0[r] += cf0[r]; net1[r] += cf1[r]; }
        }

        // transpose relu(net): C-layout -> [pt][ch]   (wave-private)
        #pragma unroll
        for (int r = 0; r < 4; ++r) {
            myxb[(q * 4 + r) * 36 + cch]      = fmaxf(net0[r], 0.0f);
            myxb[(q * 4 + r) * 36 + 16 + cch] = fmaxf(net1[r], 0.0f);
        }
        lds_fence();
        ABfrag A1;
        {
            const float* row = myxb + cch * 36 + 8 * q;   // pt = cch, k = 8q+j
            const f32x4 alo = *(const f32x4*)(row);
            const f32x4 ahi = *(const f32x4*)(row + 4);
            A1.u[0] = pk2(alo[0], alo[1]);
            A1.u[1] = pk2(alo[2], alo[3]);
            A1.u[2] = pk2(ahi[0], ahi[1]);
            A1.u[3] = pk2(ahi[2], ahi[3]);
        }

        // h = relu(net) @ W0 + b0   (bias via C operand; B from LDS table)
        f32x4 h0 = { bc00, bc00, bc00, bc00 };
        f32x4 h1 = { bc01, bc01, bc01, bc01 };
        {
            ABfrag B0a, B0b;
            const uint4 wa = wtab[(s * 4 + 0) * 64 + lane];
            const uint4 wb = wtab[(s * 4 + 1) * 64 + lane];
            B0a.u[0] = wa.x; B0a.u[1] = wa.y; B0a.u[2] = wa.z; B0a.u[3] = wa.w;
            B0b.u[0] = wb.x; B0b.u[1] = wb.y; B0b.u[2] = wb.z; B0b.u[3] = wb.w;
            h0 = __builtin_amdgcn_mfma_f32_16x16x32_bf16(A1.v, B0a.v, h0, 0, 0, 0);
            h1 = __builtin_amdgcn_mfma_f32_16x16x32_bf16(A1.v, B0b.v, h1, 0, 0, 0);
        }

        // transpose relu(h)  (A1 reads already consumed -> WAR safe)
        #pragma unroll
        for (int r = 0; r < 4; ++r) {
            myxb[(q * 4 + r) * 36 + cch]      = fmaxf(h0[r], 0.0f);
            myxb[(q * 4 + r) * 36 + 16 + cch] = fmaxf(h1[r], 0.0f);
        }
        lds_fence();
        ABfrag A2;
        {
            const float* row = myxb + cch * 36 + 8 * q;
            const f32x4 alo = *(const f32x4*)(row);
            const f32x4 ahi = *(const f32x4*)(row + 4);
            A2.u[0] = pk2(alo[0], alo[1]);
            A2.u[1] = pk2(alo[2], alo[3]);
            A2.u[2] = pk2(ahi[0], ahi[1]);
            A2.u[3] = pk2(ahi[2], ahi[3]);
        }

        // net = (net + b1) + relu(h) @ W1   (residual via C operand)
        #pragma unroll
        for (int r = 0; r < 4; ++r) { net0[r] += bc10; net1[r] += bc11; }
        {
            ABfrag B1a, B1b;
            const uint4 wa = wtab[(s * 4 + 2) * 64 + lane];
            const uint4 wb = wtab[(s * 4 + 3) * 64 + lane];
            B1a.u[0] = wa.x; B1a.u[1] = wa.y; B1a.u[2] = wa.z; B1a.u[3] = wa.w;
            B1b.u[0] = wb.x; B1b.u[1] = wb.y; B1b.u[2] = wb.z; B1b.u[3] = wb.w;
            net0 = __builtin_amdgcn_mfma_f32_16x16x32_bf16(A2.v, B1a.v, net0, 0, 0, 0);
            net1 = __builtin_amdgcn_mfma_f32_16x16x32_bf16(A2.v, B1b.v, net1, 0, 0, 0);
        }
    }

    // ---------------------------------------------------------- fc_out -----
    const float wo0 = fc_out_W[cch];
    const float wo1 = fc_out_W[16 + cch];
    float acc[4];
    #pragma unroll
    for (int r = 0; r < 4; ++r)
        acc[r] = fmaxf(net0[r], 0.0f) * wo0 + fmaxf(net1[r], 0.0f) * wo1;
    #pragma unroll
    for (int m = 1; m < 16; m <<= 1) {
        #pragma unroll
        for (int r = 0; r < 4; ++r) acc[r] += __shfl_xor(acc[r], m, 64);
    }
    if (cch == 0) {
        const float ob = fc_out_b[0];
        #pragma unroll
        for (int r = 0; r < 4; ++r) out[tpt + q * 4 + r] = acc[r] + ob;
    }
}

extern "C" void kernel_launch(void* const* d_in, const int* in_sizes, int n_in,
                              void* d_out, int out_size, void* d_ws, size_t ws_size,
                              hipStream_t stream) {
    const float* p        = (const float*)d_in[0];
    // d_in[1] = z  -- unused by the reference
    const float* c        = (const float*)d_in[2];
    const float* Cmat     = (const float*)d_in[3];
    const float* fc_p_W   = (const float*)d_in[4];
    const float* fc_p_b   = (const float*)d_in[5];
    const float* W0       = (const float*)d_in[6];
    const float* b0       = (const float*)d_in[7];
    const float* W1       = (const float*)d_in[8];
    const float* b1       = (const float*)d_in[9];
    const float* fc_out_W = (const float*)d_in[10];
    const float* fc_out_b = (const float*)d_in[11];
    float* out = (float*)d_out;

    // 128 points/block, 512 threads/block -> 512 blocks (2 blocks/CU)
    decoder_fused_mfma<<<NPT / 128, 512, 0, stream>>>(p, c, Cmat, fc_p_W, fc_p_b,
                                                      W0, b0, W1, b1, fc_out_W, fc_out_b, out);
}